// Round 4
// baseline (539.252 us; speedup 1.0000x reference)
//
#include <hip/hip_runtime.h>

typedef __bf16 bf16x8 __attribute__((ext_vector_type(8)));
typedef __bf16 bf16x2 __attribute__((ext_vector_type(2)));
typedef float f32x4 __attribute__((ext_vector_type(4)));
typedef unsigned u32x4v __attribute__((ext_vector_type(4)));

#define MFMA16(a, b, c) __builtin_amdgcn_mfma_f32_16x16x32_bf16(a, b, c, 0, 0, 0)
#define LOG2E 1.4426950408889634f

typedef __attribute__((address_space(3))) void lds_void;
typedef __attribute__((address_space(1))) const void gbl_void;
__device__ inline void glds16(const __bf16* g, __bf16* l) {
  __builtin_amdgcn_global_load_lds((gbl_void*)g, (lds_void*)l, 16, 0, 0);
}

__device__ inline unsigned pk2(float a, float b) {
  bf16x2 t; t[0] = (__bf16)a; t[1] = (__bf16)b;
  return __builtin_bit_cast(unsigned, t);
}

// Convert f32 -> bf16 with scale, 8 elements per thread.
__global__ void cvt_scale(const float* __restrict__ src, __bf16* __restrict__ dst,
                          int n8, float scale) {
  int i = blockIdx.x * blockDim.x + threadIdx.x;
  if (i >= n8) return;
  const float4* p = (const float4*)(src + i * 8);
  float4 a = p[0], b = p[1];
  bf16x8 r;
  r[0] = (__bf16)(a.x * scale); r[1] = (__bf16)(a.y * scale);
  r[2] = (__bf16)(a.z * scale); r[3] = (__bf16)(a.w * scale);
  r[4] = (__bf16)(b.x * scale); r[5] = (__bf16)(b.y * scale);
  r[6] = (__bf16)(b.z * scale); r[7] = (__bf16)(b.w * scale);
  *(bf16x8*)(dst + i * 8) = r;
}

// Pack rel-pos bias into the MFMA *A-operand* layout for the identity-MFMA
// bias+mask add.  Table[h]: [qt][c][half][qd][l15][8]:
//   value = bias(q = qt*16 + qd*8 + e, key = c*32 + krow(l15) + half*4)
// with krow(l15) = (l15>>2)*8 + (l15&3); pre-scaled by log2(e); pad -> -1e30.
// At runtime lanes with quad<2 read this table (k-slots 0..15 of the A-frag).
__global__ void pack_bias(const float* __restrict__ rpb, __bf16* __restrict__ dst) {
  int i = blockIdx.x * blockDim.x + threadIdx.x;
  if (i >= 16 * 15488) return;
  int h = i / 15488, rem = i % 15488;   // 15488 = 22*11*2*2*16
  int qt = rem / 704, rem2 = rem % 704; // 704 = 11*2*2*16
  int c = rem2 / 64, rem3 = rem2 % 64;
  int half = rem3 >> 5, qd = (rem3 >> 4) & 1, l15 = rem3 & 15;
  int key = c * 32 + (l15 >> 2) * 8 + (l15 & 3) + half * 4;
  bf16x8 v;
#pragma unroll
  for (int e = 0; e < 8; e++) {
    int q = qt * 16 + qd * 8 + e;
    float val = -1e30f;
    if (q < 343 && key < 343) {
      int q0 = q / 49, q1 = (q / 7) % 7, q2 = q % 7;
      int k0 = key / 49, k1 = (key / 7) % 7, k2 = key % 7;
      int idx = ((q0 - k0 + 6) * 13 + (q1 - k1 + 6)) * 13 + (q2 - k2 + 6);
      val = rpb[idx * 16 + h] * LOG2E;
    }
    v[e] = (__bf16)val;
  }
  *(bf16x8*)(dst + i * 8) = v;
}

// Same A-operand packing for the window mask (read by lanes quad>=2,
// k-slots 16..31): [w][qt][c][half][qd][l15][8].
__global__ void pack_mask(const float* __restrict__ mask, __bf16* __restrict__ dst) {
  int i = blockIdx.x * blockDim.x + threadIdx.x;
  if (i >= 64 * 15488) return;
  int w = i / 15488, rem = i % 15488;
  int qt = rem / 704, rem2 = rem % 704;
  int c = rem2 / 64, rem3 = rem2 % 64;
  int half = rem3 >> 5, qd = (rem3 >> 4) & 1, l15 = rem3 & 15;
  int key = c * 32 + (l15 >> 2) * 8 + (l15 & 3) + half * 4;
  const float* s = mask + w * 117649;
  bf16x8 v;
#pragma unroll
  for (int e = 0; e < 8; e++) {
    int q = qt * 16 + qd * 8 + e;
    float val = (q < 343 && key < 343) ? s[q * 343 + key] * LOG2E : -1e30f;
    v[e] = (__bf16)val;
  }
  *(bf16x8*)(dst + i * 8) = v;
}

// C = A(MxK) @ B(NxK)^T, 128x128 tile, BK=32, 256 threads (4 waves).
// MODE 0: A is f32 (x) -> convert during reg-staged LDS write; scatter
//         epilogue -> K,V bf16 [b][h][n][hd].
// MODE 1: A bf16 via global_load_lds; +bias, f32 out.
// Bijective XCD swizzle on the linear block id (A-panel sharers -> same L2).
template <int MODE>
__global__ void __launch_bounds__(256, 2)
gemm_async(const void* __restrict__ Araw, const __bf16* __restrict__ B, const int K,
           void* __restrict__ out0, void* __restrict__ out1,
           const float* __restrict__ pbias) {
  __shared__ __bf16 As[128 * 32];
  __shared__ __bf16 Bs[128 * 32];
  const int tid = threadIdx.x;
  const int lane = tid & 63, wave = tid >> 6;
  const int quad = lane >> 4, l15 = lane & 15;
  const int wm = wave >> 1, wn = wave & 1;
  const int nwg = gridDim.x * gridDim.y;
  int bid = blockIdx.y * gridDim.x + blockIdx.x;
  {
    const int xcd = bid & 7, idx = bid >> 3, qq = nwg >> 3, rr = nwg & 7;
    bid = (xcd < rr ? xcd * (qq + 1) : rr * (qq + 1) + (xcd - rr) * qq) + idx;
  }
  const int m0 = (bid / gridDim.x) * 128, n0 = (bid % gridDim.x) * 128;
  const int sr = lane >> 2, sc = (lane & 3) * 8;
  const __bf16* Bb = B + (n0 + wave * 16 + sr) * K + sc;
  __bf16* Bsl = Bs + wave * 512;  // wave-uniform LDS base; HW adds lane*16B
  const __bf16* Ab = nullptr; const float* Af = nullptr;
  __bf16* Asl = As + wave * 512;
  if constexpr (MODE == 0) {
    Af = (const float*)Araw + (size_t)(m0 + wave * 16 + sr) * K + sc;
  } else {
    Ab = (const __bf16*)Araw + (size_t)(m0 + wave * 16 + sr) * K + sc;
  }
  f32x4 acc[4][4] = {};
  for (int k0 = 0; k0 < K; k0 += 32) {
    if constexpr (MODE == 0) {
      // reg-staged f32 -> bf16 conversion; layout identical to glds16 path
      float4 a0 = *(const float4*)(Af + k0), a1 = *(const float4*)(Af + k0 + 4);
      float4 b0 = *(const float4*)(Af + (size_t)64 * K + k0);
      float4 b1 = *(const float4*)(Af + (size_t)64 * K + k0 + 4);
      bf16x8 c0, c1;
      c0[0] = (__bf16)a0.x; c0[1] = (__bf16)a0.y; c0[2] = (__bf16)a0.z; c0[3] = (__bf16)a0.w;
      c0[4] = (__bf16)a1.x; c0[5] = (__bf16)a1.y; c0[6] = (__bf16)a1.z; c0[7] = (__bf16)a1.w;
      c1[0] = (__bf16)b0.x; c1[1] = (__bf16)b0.y; c1[2] = (__bf16)b0.z; c1[3] = (__bf16)b0.w;
      c1[4] = (__bf16)b1.x; c1[5] = (__bf16)b1.y; c1[6] = (__bf16)b1.z; c1[7] = (__bf16)b1.w;
      *(bf16x8*)(As + (wave * 16 + sr) * 32 + sc) = c0;
      *(bf16x8*)(As + (64 + wave * 16 + sr) * 32 + sc) = c1;
    } else {
      glds16(Ab + k0, Asl);
      glds16(Ab + 64 * K + k0, Asl + 2048);
    }
    glds16(Bb + k0, Bsl);
    glds16(Bb + 64 * K + k0, Bsl + 2048);
    __syncthreads();  // drains vmcnt + lgkmcnt -> staged data visible
    bf16x8 af[4], bfr[4];
#pragma unroll
    for (int i = 0; i < 4; i++) {
      af[i] = *(const bf16x8*)(As + (wm * 64 + i * 16 + l15) * 32 + quad * 8);
      bfr[i] = *(const bf16x8*)(Bs + (wn * 64 + i * 16 + l15) * 32 + quad * 8);
    }
#pragma unroll
    for (int i = 0; i < 4; i++)
#pragma unroll
      for (int j = 0; j < 4; j++)
        acc[i][j] = MFMA16(af[i], bfr[j], acc[i][j]);
    __syncthreads();  // protect LDS before next stage
  }
#pragma unroll
  for (int i = 0; i < 4; i++) {
    const int rowb = m0 + wm * 64 + i * 16 + quad * 4;
#pragma unroll
    for (int r = 0; r < 4; r++) {
      const int row = rowb + r;
      if constexpr (MODE == 0) {
        const int bb = row / 343, pos = row % 343;
#pragma unroll
        for (int j = 0; j < 4; j++) {
          const int col = n0 + wn * 64 + j * 16 + l15;
          const int two = col >> 9, hh = (col >> 5) & 15, d = col & 31;
          __bf16* dst = two ? (__bf16*)out1 : (__bf16*)out0;
          dst[((bb * 16 + hh) * 343 + pos) * 32 + d] = (__bf16)acc[i][j][r];
        }
      } else {
        float* o = (float*)out0;
#pragma unroll
        for (int j = 0; j < 4; j++) {
          const int col = n0 + wn * 64 + j * 16 + l15;
          o[row * 512 + col] = acc[i][j][r] + pbias[col];
        }
      }
    }
  }
}

// One workgroup per (b, h). Swapped QK^T (S^T = mfma(K, Q)) with PERMUTED key
// order so the S^T C-fragment IS the PV A-fragment after bf16 packing.
// Bias+mask are added via an extra MFMA per S-half: tables packed in A-operand
// layout (quads 0-1 = bias columns k=0..15, quads 2-3 = mask columns 16..31),
// multiplied by the constant selector B-frag B[k][j] = (k%16 == j), so
// (A.B)[key][q] = bias+mask lands in the C-preload on the matrix pipe
// (replaces ~24 VALU unpack/add ops per iteration).
// K bulk-staged in LDS (round-2 best); V transposed in LDS.
__global__ void __launch_bounds__(512, 6)
attn_win(const __bf16* __restrict__ qs, const __bf16* __restrict__ kk,
         const __bf16* __restrict__ vv, const __bf16* __restrict__ bias_pk,
         const __bf16* __restrict__ mask_pk, __bf16* __restrict__ ao) {
  __shared__ __bf16 Ks[352 * 40];    // keys padded to 352 rows, stride 40
  __shared__ __bf16 Vt[32 * 360];    // V transposed [hd][key], stride 360
  const int bid = blockIdx.x;
  const int bh = (bid & 7) * 256 + (bid >> 3);  // XCD swizzle (2048 % 8 == 0)
  const int b = bh >> 4, h = bh & 15;
  const int tid = threadIdx.x;
  const int lane = tid & 63, wave = tid >> 6;
  const int quad = lane >> 4, l15 = lane & 15;
  const __bf16* ksrc = kk + (b * 16 + h) * 10976;
  const __bf16* vsrc = vv + (b * 16 + h) * 10976;
  for (int i = tid; i < 352 * 4; i += 512) {
    const int row = i >> 2, seg = (i & 3) * 8;
    bf16x8 val;
    if (row < 343) {
      val = *(const bf16x8*)(ksrc + row * 32 + seg);
    } else {
#pragma unroll
      for (int e = 0; e < 8; e++) val[e] = (__bf16)0.f;
    }
    *(bf16x8*)(Ks + row * 40 + seg) = val;
  }
  // zero-pad Vt cols 343..358 (reads reach col 351)
  Vt[(tid >> 4) * 360 + 343 + (tid & 15)] = (__bf16)0.f;
  for (int i = tid; i < 1372; i += 512) {  // 10976/8 vectorized transpose
    const int pos = i >> 2, seg = (i & 3) * 8;
    bf16x8 v = *(const bf16x8*)(vsrc + pos * 32 + seg);
#pragma unroll
    for (int e = 0; e < 8; e++) Vt[(seg + e) * 360 + pos] = v[e];
  }

  const int b2 = b >> 6, w = b & 63;
  const __bf16* qbase = qs + (b2 * 16 + h) * 10976;
  // per-lane table base: bias for quads 0-1, mask for quads 2-3
  const __bf16* tab = (quad < 2 ? bias_pk + h * 123904 : mask_pk + w * 123904)
                      + (quad & 1) * 128 + l15 * 8;
  const int nqt = (wave < 6) ? 3 : 2;  // 22 q-tiles over 8 waves

  bf16x8 aq[3];
#pragma unroll
  for (int t = 0; t < 3; t++) {
    int qt = wave + 8 * t; if (qt > 21) qt = 21;
    const int arow = qt * 16 + l15;
    const int arowc = arow < 343 ? arow : 342;  // clamp; padded rows discarded
    aq[t] = *(const bf16x8*)(qbase + arowc * 32 + quad * 8);
  }
  bf16x8 ones;  // B-frag of the "ones column": col 0 = 1, rest 0
  bf16x8 idf;   // selector B-frag: B[k][j] = (k%16 == j)
  {
    const __bf16 ov = (l15 == 0) ? (__bf16)1.f : (__bf16)0.f;
#pragma unroll
    for (int e = 0; e < 8; e++) {
      ones[e] = ov;
      idf[e] = ((quad & 1) * 8 + e == l15) ? (__bf16)1.f : (__bf16)0.f;
    }
  }
  const int krow = (l15 >> 2) * 8 + (l15 & 3);  // permuted key-row order
  __syncthreads();

  f32x4 o0[3], o1[3], o2[3];
#pragma unroll
  for (int t = 0; t < 3; t++)
#pragma unroll
    for (int r = 0; r < 4; r++) { o0[t][r] = 0.f; o1[t][r] = 0.f; o2[t][r] = 0.f; }

  for (int c = 0; c < 11; c++) {  // 11 chunks of 32 keys
    const bf16x8 bk0 = *(const bf16x8*)(Ks + (c * 32 + krow) * 40 + quad * 8);
    const bf16x8 bk1 = *(const bf16x8*)(Ks + (c * 32 + krow + 4) * 40 + quad * 8);
    const bf16x8 bv0 = *(const bf16x8*)(Vt + l15 * 360 + c * 32 + quad * 8);
    const bf16x8 bv1 = *(const bf16x8*)(Vt + (16 + l15) * 360 + c * 32 + quad * 8);
#pragma unroll
    for (int t = 0; t < 3; t++) {
      if (t >= nqt) break;
      const int qt = wave + 8 * t;
      const __bf16* tb = tab + (qt * 11 + c) * 512;
      const bf16x8 f0 = *(const bf16x8*)tb;          // A-frag, keys krow+0
      const bf16x8 f1 = *(const bf16x8*)(tb + 256);  // A-frag, keys krow+4
      const f32x4 z = {0.f, 0.f, 0.f, 0.f};
      __builtin_amdgcn_s_setprio(1);
      f32x4 s0 = MFMA16(f0, idf, z);   // C preload = bias+mask (log2 domain)
      f32x4 s1 = MFMA16(f1, idf, z);
      s0 = MFMA16(bk0, aq[t], s0);     // swapped: rows=keys (permuted), cols=q
      s1 = MFMA16(bk1, aq[t], s1);
#pragma unroll
      for (int r = 0; r < 4; r++) {
        s0[r] = __builtin_amdgcn_exp2f(s0[r]);
        s1[r] = __builtin_amdgcn_exp2f(s1[r]);
      }
      // S^T fragment (permuted key order) IS the PV A-fragment: just pack.
      u32x4v uv;
      uv[0] = pk2(s0[0], s0[1]); uv[1] = pk2(s0[2], s0[3]);
      uv[2] = pk2(s1[0], s1[1]); uv[3] = pk2(s1[2], s1[3]);
      const bf16x8 ap = __builtin_bit_cast(bf16x8, uv);
      o0[t] = MFMA16(ap, bv0, o0[t]);
      o1[t] = MFMA16(ap, bv1, o1[t]);
      o2[t] = MFMA16(ap, ones, o2[t]);  // row-sum of P via matrix pipe
      __builtin_amdgcn_s_setprio(0);
    }
  }

#pragma unroll
  for (int t = 0; t < 3; t++) {
    if (t >= nqt) break;
    const int qt = wave + 8 * t;
#pragma unroll
    for (int r = 0; r < 4; r++) {
      const float lsum = __shfl(o2[t][r], lane & 48);  // from l15==0 of my quad
      const float inv = __builtin_amdgcn_rcpf(lsum);
      const int row = qt * 16 + quad * 4 + r;
      if (row < 343) {
        __bf16* op = ao + (b * 343 + row) * 512 + h * 32;
        op[l15] = (__bf16)(o0[t][r] * inv);
        op[16 + l15] = (__bf16)(o1[t][r] * inv);
      }
    }
  }
}

extern "C" void kernel_launch(void* const* d_in, const int* in_sizes, int n_in,
                              void* d_out, int out_size, void* d_ws, size_t ws_size,
                              hipStream_t stream) {
  (void)in_sizes; (void)n_in; (void)out_size; (void)ws_size;
  const float* x      = (const float*)d_in[0];
  const float* mask   = (const float*)d_in[4];
  const float* qg     = (const float*)d_in[5];
  const float* kv_w   = (const float*)d_in[6];
  const float* proj_w = (const float*)d_in[7];
  const float* proj_b = (const float*)d_in[8];
  const float* rpb    = (const float*)d_in[9];

  // Workspace layout (16B aligned). x is consumed directly (f32) by gemm0's
  // fused convert staging; aob occupies the slot xb used to hold.
  char* ws = (char*)d_ws;
  __bf16* q_bf    = (__bf16*)(ws);               //    702,464  q*scale*log2e [2][16][343][32]
  __bf16* bias_pk = (__bf16*)(ws + 702464);      //  3,964,928  [16][22][11][2][2][16][8]
  __bf16* mask_pk = (__bf16*)(ws + 4667392);     // 15,859,712  [64][22][11][2][2][16][8]
  __bf16* kvw_b   = (__bf16*)(ws + 20527104);    //  1,048,576
  __bf16* projw_b = (__bf16*)(ws + 21575680);    //    524,288
  __bf16* kb      = (__bf16*)(ws + 22099968);    // 44,957,696  K bf16 [128][16][343][32]
  __bf16* vb      = (__bf16*)(ws + 67057664);    // 44,957,696  V bf16
  __bf16* aob     = (__bf16*)(ws + 112015360);   // 44,957,696  attn out bf16

  const float QSCALE = 0.17677669529663687f * LOG2E;  // hd^-0.5 * log2(e)

  cvt_scale<<<172, 256, 0, stream>>>(qg, q_bf, 43904, QSCALE);   // 351,232 elems = 43904*8
  cvt_scale<<<256, 256, 0, stream>>>(kv_w, kvw_b, 65536, 1.f);
  cvt_scale<<<128, 256, 0, stream>>>(proj_w, projw_b, 32768, 1.f);
  pack_bias<<<968, 256, 0, stream>>>(rpb, bias_pk);
  pack_mask<<<3872, 256, 0, stream>>>(mask, mask_pk);
  gemm_async<0><<<dim3(8, 343), 256, 0, stream>>>(x, kvw_b, 512, kb, vb, nullptr);
  attn_win<<<2048, 512, 0, stream>>>(q_bf, kb, vb, bias_pk, mask_pk, aob);
  gemm_async<1><<<dim3(4, 343), 256, 0, stream>>>(aob, projw_b, 512, d_out, nullptr, proj_b);
}

// Round 5
// 400.875 us; speedup vs baseline: 1.3452x; 1.3452x over previous
//
#include <hip/hip_runtime.h>

typedef __bf16 bf16x8 __attribute__((ext_vector_type(8)));
typedef __bf16 bf16x2 __attribute__((ext_vector_type(2)));
typedef float f32x4 __attribute__((ext_vector_type(4)));
typedef unsigned u32x4v __attribute__((ext_vector_type(4)));

#define MFMA16(a, b, c) __builtin_amdgcn_mfma_f32_16x16x32_bf16(a, b, c, 0, 0, 0)
#define LOG2E 1.4426950408889634f

typedef __attribute__((address_space(3))) void lds_void;
typedef __attribute__((address_space(1))) const void gbl_void;
__device__ inline void glds16(const __bf16* g, __bf16* l) {
  __builtin_amdgcn_global_load_lds((gbl_void*)g, (lds_void*)l, 16, 0, 0);
}

__device__ inline unsigned pk2(float a, float b) {
  bf16x2 t; t[0] = (__bf16)a; t[1] = (__bf16)b;
  return __builtin_bit_cast(unsigned, t);
}

// Convert f32 -> bf16 with scale, 8 elements per thread.
__global__ void cvt_scale(const float* __restrict__ src, __bf16* __restrict__ dst,
                          int n8, float scale) {
  int i = blockIdx.x * blockDim.x + threadIdx.x;
  if (i >= n8) return;
  const float4* p = (const float4*)(src + i * 8);
  float4 a = p[0], b = p[1];
  bf16x8 r;
  r[0] = (__bf16)(a.x * scale); r[1] = (__bf16)(a.y * scale);
  r[2] = (__bf16)(a.z * scale); r[3] = (__bf16)(a.w * scale);
  r[4] = (__bf16)(b.x * scale); r[5] = (__bf16)(b.y * scale);
  r[6] = (__bf16)(b.z * scale); r[7] = (__bf16)(b.w * scale);
  *(bf16x8*)(dst + i * 8) = r;
}

// Pack rel-pos bias into the MFMA *A-operand* layout for the identity-MFMA
// bias+mask add.  Table[h]: [qt][c][half][qd][l15][8]:
//   value = bias(q = qt*16 + qd*8 + e, key = c*32 + krow(l15) + half*4)
// with krow(l15) = (l15>>2)*8 + (l15&3); pre-scaled by log2(e); pad -> -1e30.
// At runtime lanes with quad<2 read this table (k-slots 0..15 of the A-frag).
__global__ void pack_bias(const float* __restrict__ rpb, __bf16* __restrict__ dst) {
  int i = blockIdx.x * blockDim.x + threadIdx.x;
  if (i >= 16 * 15488) return;
  int h = i / 15488, rem = i % 15488;   // 15488 = 22*11*2*2*16
  int qt = rem / 704, rem2 = rem % 704; // 704 = 11*2*2*16
  int c = rem2 / 64, rem3 = rem2 % 64;
  int half = rem3 >> 5, qd = (rem3 >> 4) & 1, l15 = rem3 & 15;
  int key = c * 32 + (l15 >> 2) * 8 + (l15 & 3) + half * 4;
  bf16x8 v;
#pragma unroll
  for (int e = 0; e < 8; e++) {
    int q = qt * 16 + qd * 8 + e;
    float val = -1e30f;
    if (q < 343 && key < 343) {
      int q0 = q / 49, q1 = (q / 7) % 7, q2 = q % 7;
      int k0 = key / 49, k1 = (key / 7) % 7, k2 = key % 7;
      int idx = ((q0 - k0 + 6) * 13 + (q1 - k1 + 6)) * 13 + (q2 - k2 + 6);
      val = rpb[idx * 16 + h] * LOG2E;
    }
    v[e] = (__bf16)val;
  }
  *(bf16x8*)(dst + i * 8) = v;
}

// Same A-operand packing for the window mask (read by lanes quad>=2,
// k-slots 16..31): [w][qt][c][half][qd][l15][8].
__global__ void pack_mask(const float* __restrict__ mask, __bf16* __restrict__ dst) {
  int i = blockIdx.x * blockDim.x + threadIdx.x;
  if (i >= 64 * 15488) return;
  int w = i / 15488, rem = i % 15488;
  int qt = rem / 704, rem2 = rem % 704;
  int c = rem2 / 64, rem3 = rem2 % 64;
  int half = rem3 >> 5, qd = (rem3 >> 4) & 1, l15 = rem3 & 15;
  int key = c * 32 + (l15 >> 2) * 8 + (l15 & 3) + half * 4;
  const float* s = mask + w * 117649;
  bf16x8 v;
#pragma unroll
  for (int e = 0; e < 8; e++) {
    int q = qt * 16 + qd * 8 + e;
    float val = (q < 343 && key < 343) ? s[q * 343 + key] * LOG2E : -1e30f;
    v[e] = (__bf16)val;
  }
  *(bf16x8*)(dst + i * 8) = v;
}

// C = A(MxK) @ B(NxK)^T, 128x128 tile, BK=32, 256 threads (4 waves).
// MODE 0: A is f32 (x) -> convert during reg-staged LDS write; scatter
//         epilogue -> K,V bf16 [b][h][n][hd].
// MODE 1: A bf16 via global_load_lds; +bias, f32 out.
// Bijective XCD swizzle on the linear block id (A-panel sharers -> same L2).
template <int MODE>
__global__ void __launch_bounds__(256, 2)
gemm_async(const void* __restrict__ Araw, const __bf16* __restrict__ B, const int K,
           void* __restrict__ out0, void* __restrict__ out1,
           const float* __restrict__ pbias) {
  __shared__ __bf16 As[128 * 32];
  __shared__ __bf16 Bs[128 * 32];
  const int tid = threadIdx.x;
  const int lane = tid & 63, wave = tid >> 6;
  const int quad = lane >> 4, l15 = lane & 15;
  const int wm = wave >> 1, wn = wave & 1;
  const int nwg = gridDim.x * gridDim.y;
  int bid = blockIdx.y * gridDim.x + blockIdx.x;
  {
    const int xcd = bid & 7, idx = bid >> 3, qq = nwg >> 3, rr = nwg & 7;
    bid = (xcd < rr ? xcd * (qq + 1) : rr * (qq + 1) + (xcd - rr) * qq) + idx;
  }
  const int m0 = (bid / gridDim.x) * 128, n0 = (bid % gridDim.x) * 128;
  const int sr = lane >> 2, sc = (lane & 3) * 8;
  const __bf16* Bb = B + (n0 + wave * 16 + sr) * K + sc;
  __bf16* Bsl = Bs + wave * 512;  // wave-uniform LDS base; HW adds lane*16B
  const __bf16* Ab = nullptr; const float* Af = nullptr;
  __bf16* Asl = As + wave * 512;
  if constexpr (MODE == 0) {
    Af = (const float*)Araw + (size_t)(m0 + wave * 16 + sr) * K + sc;
  } else {
    Ab = (const __bf16*)Araw + (size_t)(m0 + wave * 16 + sr) * K + sc;
  }
  f32x4 acc[4][4] = {};
  for (int k0 = 0; k0 < K; k0 += 32) {
    if constexpr (MODE == 0) {
      // reg-staged f32 -> bf16 conversion; layout identical to glds16 path
      float4 a0 = *(const float4*)(Af + k0), a1 = *(const float4*)(Af + k0 + 4);
      float4 b0 = *(const float4*)(Af + (size_t)64 * K + k0);
      float4 b1 = *(const float4*)(Af + (size_t)64 * K + k0 + 4);
      bf16x8 c0, c1;
      c0[0] = (__bf16)a0.x; c0[1] = (__bf16)a0.y; c0[2] = (__bf16)a0.z; c0[3] = (__bf16)a0.w;
      c0[4] = (__bf16)a1.x; c0[5] = (__bf16)a1.y; c0[6] = (__bf16)a1.z; c0[7] = (__bf16)a1.w;
      c1[0] = (__bf16)b0.x; c1[1] = (__bf16)b0.y; c1[2] = (__bf16)b0.z; c1[3] = (__bf16)b0.w;
      c1[4] = (__bf16)b1.x; c1[5] = (__bf16)b1.y; c1[6] = (__bf16)b1.z; c1[7] = (__bf16)b1.w;
      *(bf16x8*)(As + (wave * 16 + sr) * 32 + sc) = c0;
      *(bf16x8*)(As + (64 + wave * 16 + sr) * 32 + sc) = c1;
    } else {
      glds16(Ab + k0, Asl);
      glds16(Ab + 64 * K + k0, Asl + 2048);
    }
    glds16(Bb + k0, Bsl);
    glds16(Bb + 64 * K + k0, Bsl + 2048);
    __syncthreads();  // drains vmcnt + lgkmcnt -> staged data visible
    bf16x8 af[4], bfr[4];
#pragma unroll
    for (int i = 0; i < 4; i++) {
      af[i] = *(const bf16x8*)(As + (wm * 64 + i * 16 + l15) * 32 + quad * 8);
      bfr[i] = *(const bf16x8*)(Bs + (wn * 64 + i * 16 + l15) * 32 + quad * 8);
    }
#pragma unroll
    for (int i = 0; i < 4; i++)
#pragma unroll
      for (int j = 0; j < 4; j++)
        acc[i][j] = MFMA16(af[i], bfr[j], acc[i][j]);
    __syncthreads();  // protect LDS before next stage
  }
#pragma unroll
  for (int i = 0; i < 4; i++) {
    const int rowb = m0 + wm * 64 + i * 16 + quad * 4;
#pragma unroll
    for (int r = 0; r < 4; r++) {
      const int row = rowb + r;
      if constexpr (MODE == 0) {
        const int bb = row / 343, pos = row % 343;
#pragma unroll
        for (int j = 0; j < 4; j++) {
          const int col = n0 + wn * 64 + j * 16 + l15;
          const int two = col >> 9, hh = (col >> 5) & 15, d = col & 31;
          __bf16* dst = two ? (__bf16*)out1 : (__bf16*)out0;
          dst[((bb * 16 + hh) * 343 + pos) * 32 + d] = (__bf16)acc[i][j][r];
        }
      } else {
        float* o = (float*)out0;
#pragma unroll
        for (int j = 0; j < 4; j++) {
          const int col = n0 + wn * 64 + j * 16 + l15;
          o[row * 512 + col] = acc[i][j][r] + pbias[col];
        }
      }
    }
  }
}

// One workgroup per (b, h). Swapped QK^T (S^T = mfma(K, Q)) with PERMUTED key
// order so the S^T C-fragment IS the PV A-fragment after bf16 packing.
// Bias+mask are added via an extra MFMA per S-half: tables packed in A-operand
// layout (quads 0-1 = bias columns k=0..15, quads 2-3 = mask columns 16..31),
// multiplied by the constant selector B-frag B[k][j] = (k%16 == j), so
// (A.B)[key][q] = bias+mask lands in the C-preload on the matrix pipe.
// K bulk-staged in LDS; V transposed in LDS.
// launch_bounds (512,4): cap 128 regs -- (512,6)'s 85-reg cap caused massive
// scratch spilling (round-4: WRITE_SIZE 44->470 MB, dur 96->231 us).
__global__ void __launch_bounds__(512, 4)
attn_win(const __bf16* __restrict__ qs, const __bf16* __restrict__ kk,
         const __bf16* __restrict__ vv, const __bf16* __restrict__ bias_pk,
         const __bf16* __restrict__ mask_pk, __bf16* __restrict__ ao) {
  __shared__ __bf16 Ks[352 * 40];    // keys padded to 352 rows, stride 40
  __shared__ __bf16 Vt[32 * 360];    // V transposed [hd][key], stride 360
  const int bid = blockIdx.x;
  const int bh = (bid & 7) * 256 + (bid >> 3);  // XCD swizzle (2048 % 8 == 0)
  const int b = bh >> 4, h = bh & 15;
  const int tid = threadIdx.x;
  const int lane = tid & 63, wave = tid >> 6;
  const int quad = lane >> 4, l15 = lane & 15;
  const __bf16* ksrc = kk + (b * 16 + h) * 10976;
  const __bf16* vsrc = vv + (b * 16 + h) * 10976;
  for (int i = tid; i < 352 * 4; i += 512) {
    const int row = i >> 2, seg = (i & 3) * 8;
    bf16x8 val;
    if (row < 343) {
      val = *(const bf16x8*)(ksrc + row * 32 + seg);
    } else {
#pragma unroll
      for (int e = 0; e < 8; e++) val[e] = (__bf16)0.f;
    }
    *(bf16x8*)(Ks + row * 40 + seg) = val;
  }
  // zero-pad Vt cols 343..358 (reads reach col 351)
  Vt[(tid >> 4) * 360 + 343 + (tid & 15)] = (__bf16)0.f;
  for (int i = tid; i < 1372; i += 512) {  // 10976/8 vectorized transpose
    const int pos = i >> 2, seg = (i & 3) * 8;
    bf16x8 v = *(const bf16x8*)(vsrc + pos * 32 + seg);
#pragma unroll
    for (int e = 0; e < 8; e++) Vt[(seg + e) * 360 + pos] = v[e];
  }

  const int b2 = b >> 6, w = b & 63;
  const __bf16* qbase = qs + (b2 * 16 + h) * 10976;
  // per-lane table base: bias for quads 0-1, mask for quads 2-3
  const __bf16* tab = (quad < 2 ? bias_pk + h * 123904 : mask_pk + w * 123904)
                      + (quad & 1) * 128 + l15 * 8;
  const int nqt = (wave < 6) ? 3 : 2;  // 22 q-tiles over 8 waves

  bf16x8 aq[3];
#pragma unroll
  for (int t = 0; t < 3; t++) {
    int qt = wave + 8 * t; if (qt > 21) qt = 21;
    const int arow = qt * 16 + l15;
    const int arowc = arow < 343 ? arow : 342;  // clamp; padded rows discarded
    aq[t] = *(const bf16x8*)(qbase + arowc * 32 + quad * 8);
  }
  bf16x8 ones;  // B-frag of the "ones column": col 0 = 1, rest 0
  bf16x8 idf;   // selector B-frag: B[k][j] = (k%16 == j)
  {
    const __bf16 ov = (l15 == 0) ? (__bf16)1.f : (__bf16)0.f;
#pragma unroll
    for (int e = 0; e < 8; e++) {
      ones[e] = ov;
      idf[e] = ((quad & 1) * 8 + e == l15) ? (__bf16)1.f : (__bf16)0.f;
    }
  }
  const int krow = (l15 >> 2) * 8 + (l15 & 3);  // permuted key-row order
  __syncthreads();

  f32x4 o0[3], o1[3], o2[3];
#pragma unroll
  for (int t = 0; t < 3; t++)
#pragma unroll
    for (int r = 0; r < 4; r++) { o0[t][r] = 0.f; o1[t][r] = 0.f; o2[t][r] = 0.f; }

  for (int c = 0; c < 11; c++) {  // 11 chunks of 32 keys
    const bf16x8 bk0 = *(const bf16x8*)(Ks + (c * 32 + krow) * 40 + quad * 8);
    const bf16x8 bk1 = *(const bf16x8*)(Ks + (c * 32 + krow + 4) * 40 + quad * 8);
    const bf16x8 bv0 = *(const bf16x8*)(Vt + l15 * 360 + c * 32 + quad * 8);
    const bf16x8 bv1 = *(const bf16x8*)(Vt + (16 + l15) * 360 + c * 32 + quad * 8);
#pragma unroll
    for (int t = 0; t < 3; t++) {
      if (t >= nqt) break;
      const int qt = wave + 8 * t;
      const __bf16* tb = tab + (qt * 11 + c) * 512;
      const bf16x8 f0 = *(const bf16x8*)tb;          // A-frag, keys krow+0
      const bf16x8 f1 = *(const bf16x8*)(tb + 256);  // A-frag, keys krow+4
      const f32x4 z = {0.f, 0.f, 0.f, 0.f};
      __builtin_amdgcn_s_setprio(1);
      f32x4 s0 = MFMA16(f0, idf, z);   // C preload = bias+mask (log2 domain)
      f32x4 s1 = MFMA16(f1, idf, z);
      s0 = MFMA16(bk0, aq[t], s0);     // swapped: rows=keys (permuted), cols=q
      s1 = MFMA16(bk1, aq[t], s1);
#pragma unroll
      for (int r = 0; r < 4; r++) {
        s0[r] = __builtin_amdgcn_exp2f(s0[r]);
        s1[r] = __builtin_amdgcn_exp2f(s1[r]);
      }
      // S^T fragment (permuted key order) IS the PV A-fragment: just pack.
      u32x4v uv;
      uv[0] = pk2(s0[0], s0[1]); uv[1] = pk2(s0[2], s0[3]);
      uv[2] = pk2(s1[0], s1[1]); uv[3] = pk2(s1[2], s1[3]);
      const bf16x8 ap = __builtin_bit_cast(bf16x8, uv);
      o0[t] = MFMA16(ap, bv0, o0[t]);
      o1[t] = MFMA16(ap, bv1, o1[t]);
      o2[t] = MFMA16(ap, ones, o2[t]);  // row-sum of P via matrix pipe
      __builtin_amdgcn_s_setprio(0);
    }
  }

#pragma unroll
  for (int t = 0; t < 3; t++) {
    if (t >= nqt) break;
    const int qt = wave + 8 * t;
#pragma unroll
    for (int r = 0; r < 4; r++) {
      const float lsum = __shfl(o2[t][r], lane & 48);  // from l15==0 of my quad
      const float inv = __builtin_amdgcn_rcpf(lsum);
      const int row = qt * 16 + quad * 4 + r;
      if (row < 343) {
        __bf16* op = ao + (b * 343 + row) * 512 + h * 32;
        op[l15] = (__bf16)(o0[t][r] * inv);
        op[16 + l15] = (__bf16)(o1[t][r] * inv);
      }
    }
  }
}

extern "C" void kernel_launch(void* const* d_in, const int* in_sizes, int n_in,
                              void* d_out, int out_size, void* d_ws, size_t ws_size,
                              hipStream_t stream) {
  (void)in_sizes; (void)n_in; (void)out_size; (void)ws_size;
  const float* x      = (const float*)d_in[0];
  const float* mask   = (const float*)d_in[4];
  const float* qg     = (const float*)d_in[5];
  const float* kv_w   = (const float*)d_in[6];
  const float* proj_w = (const float*)d_in[7];
  const float* proj_b = (const float*)d_in[8];
  const float* rpb    = (const float*)d_in[9];

  // Workspace layout (16B aligned). x is consumed directly (f32) by gemm0's
  // fused convert staging; aob occupies the slot xb used to hold.
  char* ws = (char*)d_ws;
  __bf16* q_bf    = (__bf16*)(ws);               //    702,464  q*scale*log2e [2][16][343][32]
  __bf16* bias_pk = (__bf16*)(ws + 702464);      //  3,964,928  [16][22][11][2][2][16][8]
  __bf16* mask_pk = (__bf16*)(ws + 4667392);     // 15,859,712  [64][22][11][2][2][16][8]
  __bf16* kvw_b   = (__bf16*)(ws + 20527104);    //  1,048,576
  __bf16* projw_b = (__bf16*)(ws + 21575680);    //    524,288
  __bf16* kb      = (__bf16*)(ws + 22099968);    // 44,957,696  K bf16 [128][16][343][32]
  __bf16* vb      = (__bf16*)(ws + 67057664);    // 44,957,696  V bf16
  __bf16* aob     = (__bf16*)(ws + 112015360);   // 44,957,696  attn out bf16

  const float QSCALE = 0.17677669529663687f * LOG2E;  // hd^-0.5 * log2(e)

  cvt_scale<<<172, 256, 0, stream>>>(qg, q_bf, 43904, QSCALE);   // 351,232 elems = 43904*8
  cvt_scale<<<256, 256, 0, stream>>>(kv_w, kvw_b, 65536, 1.f);
  cvt_scale<<<128, 256, 0, stream>>>(proj_w, projw_b, 32768, 1.f);
  pack_bias<<<968, 256, 0, stream>>>(rpb, bias_pk);
  pack_mask<<<3872, 256, 0, stream>>>(mask, mask_pk);
  gemm_async<0><<<dim3(8, 343), 256, 0, stream>>>(x, kvw_b, 512, kb, vb, nullptr);
  attn_win<<<2048, 512, 0, stream>>>(q_bf, kb, vb, bias_pk, mask_pk, aob);
  gemm_async<1><<<dim3(4, 343), 256, 0, stream>>>(aob, projw_b, 512, d_out, nullptr, proj_b);
}

// Round 6
// 399.144 us; speedup vs baseline: 1.3510x; 1.0043x over previous
//
#include <hip/hip_runtime.h>

typedef __bf16 bf16x8 __attribute__((ext_vector_type(8)));
typedef __bf16 bf16x2 __attribute__((ext_vector_type(2)));
typedef float f32x4 __attribute__((ext_vector_type(4)));
typedef unsigned u32x4v __attribute__((ext_vector_type(4)));

#define MFMA16(a, b, c) __builtin_amdgcn_mfma_f32_16x16x32_bf16(a, b, c, 0, 0, 0)
#define LOG2E 1.4426950408889634f

typedef __attribute__((address_space(3))) void lds_void;
typedef __attribute__((address_space(1))) const void gbl_void;
__device__ inline void glds16(const __bf16* g, __bf16* l) {
  __builtin_amdgcn_global_load_lds((gbl_void*)g, (lds_void*)l, 16, 0, 0);
}

__device__ inline unsigned pk2(float a, float b) {
  bf16x2 t; t[0] = (__bf16)a; t[1] = (__bf16)b;
  return __builtin_bit_cast(unsigned, t);
}

// Convert f32 -> bf16 with scale, 8 elements per thread.
__global__ void cvt_scale(const float* __restrict__ src, __bf16* __restrict__ dst,
                          int n8, float scale) {
  int i = blockIdx.x * blockDim.x + threadIdx.x;
  if (i >= n8) return;
  const float4* p = (const float4*)(src + i * 8);
  float4 a = p[0], b = p[1];
  bf16x8 r;
  r[0] = (__bf16)(a.x * scale); r[1] = (__bf16)(a.y * scale);
  r[2] = (__bf16)(a.z * scale); r[3] = (__bf16)(a.w * scale);
  r[4] = (__bf16)(b.x * scale); r[5] = (__bf16)(b.y * scale);
  r[6] = (__bf16)(b.z * scale); r[7] = (__bf16)(b.w * scale);
  *(bf16x8*)(dst + i * 8) = r;
}

// Pack rel-pos bias into the MFMA *A-operand* layout for the identity-MFMA
// bias+mask add.  Table[h]: [qt][c][half][qd][l15][8]:
//   value = bias(q = qt*16 + qd*8 + e, key = c*32 + krow(l15) + half*4)
// with krow(l15) = (l15>>2)*8 + (l15&3); pre-scaled by log2(e); pad -> -1e30.
// At runtime lanes with quad<2 read this table (k-slots 0..15 of the A-frag).
__global__ void pack_bias(const float* __restrict__ rpb, __bf16* __restrict__ dst) {
  int i = blockIdx.x * blockDim.x + threadIdx.x;
  if (i >= 16 * 15488) return;
  int h = i / 15488, rem = i % 15488;   // 15488 = 22*11*2*2*16
  int qt = rem / 704, rem2 = rem % 704; // 704 = 11*2*2*16
  int c = rem2 / 64, rem3 = rem2 % 64;
  int half = rem3 >> 5, qd = (rem3 >> 4) & 1, l15 = rem3 & 15;
  int key = c * 32 + (l15 >> 2) * 8 + (l15 & 3) + half * 4;
  bf16x8 v;
#pragma unroll
  for (int e = 0; e < 8; e++) {
    int q = qt * 16 + qd * 8 + e;
    float val = -1e30f;
    if (q < 343 && key < 343) {
      int q0 = q / 49, q1 = (q / 7) % 7, q2 = q % 7;
      int k0 = key / 49, k1 = (key / 7) % 7, k2 = key % 7;
      int idx = ((q0 - k0 + 6) * 13 + (q1 - k1 + 6)) * 13 + (q2 - k2 + 6);
      val = rpb[idx * 16 + h] * LOG2E;
    }
    v[e] = (__bf16)val;
  }
  *(bf16x8*)(dst + i * 8) = v;
}

// Same A-operand packing for the window mask (read by lanes quad>=2,
// k-slots 16..31): [w][qt][c][half][qd][l15][8].
__global__ void pack_mask(const float* __restrict__ mask, __bf16* __restrict__ dst) {
  int i = blockIdx.x * blockDim.x + threadIdx.x;
  if (i >= 64 * 15488) return;
  int w = i / 15488, rem = i % 15488;
  int qt = rem / 704, rem2 = rem % 704;
  int c = rem2 / 64, rem3 = rem2 % 64;
  int half = rem3 >> 5, qd = (rem3 >> 4) & 1, l15 = rem3 & 15;
  int key = c * 32 + (l15 >> 2) * 8 + (l15 & 3) + half * 4;
  const float* s = mask + w * 117649;
  bf16x8 v;
#pragma unroll
  for (int e = 0; e < 8; e++) {
    int q = qt * 16 + qd * 8 + e;
    float val = (q < 343 && key < 343) ? s[q * 343 + key] * LOG2E : -1e30f;
    v[e] = (__bf16)val;
  }
  *(bf16x8*)(dst + i * 8) = v;
}

// C = A(MxK) @ B(NxK)^T, 128x128 tile, BK=64 as 2x32-wide sub-tiles
// (same 64B row stride -> same bank behavior as BK=32; half the barriers,
// 32 MFMA per drain).  256 threads (4 waves).
// MODE 0: A is f32 (x) -> reg-prefetched one K-slab ahead (loads issued
//         during previous MFMA phase), converted to bf16 on store; scatter
//         epilogue -> K,V bf16 [b][h][n][hd].
// MODE 1: A bf16 via global_load_lds; +bias, f32 out.
// B glds16 issued FIRST each iteration so B staging overlaps A staging.
// Bijective XCD swizzle on the linear block id (A-panel sharers -> same L2).
template <int MODE>
__global__ void __launch_bounds__(256, 2)
gemm_async(const void* __restrict__ Araw, const __bf16* __restrict__ B, const int K,
           void* __restrict__ out0, void* __restrict__ out1,
           const float* __restrict__ pbias) {
  __shared__ __bf16 As[2 * 128 * 32];
  __shared__ __bf16 Bs[2 * 128 * 32];
  const int tid = threadIdx.x;
  const int lane = tid & 63, wave = tid >> 6;
  const int quad = lane >> 4, l15 = lane & 15;
  const int wm = wave >> 1, wn = wave & 1;
  const int nwg = gridDim.x * gridDim.y;
  int bid = blockIdx.y * gridDim.x + blockIdx.x;
  {
    const int xcd = bid & 7, idx = bid >> 3, qq = nwg >> 3, rr = nwg & 7;
    bid = (xcd < rr ? xcd * (qq + 1) : rr * (qq + 1) + (xcd - rr) * qq) + idx;
  }
  const int m0 = (bid / gridDim.x) * 128, n0 = (bid % gridDim.x) * 128;
  const int sr = lane >> 2, sc = (lane & 3) * 8;
  const __bf16* Bb = B + (n0 + wave * 16 + sr) * K + sc;
  __bf16* Bsl = Bs + wave * 512;  // wave-uniform LDS base; HW adds lane*16B
  const __bf16* Ab = nullptr; const float* Af = nullptr;
  __bf16* Asl = As + wave * 512;
  if constexpr (MODE == 0) {
    Af = (const float*)Araw + (size_t)(m0 + wave * 16 + sr) * K + sc;
  } else {
    Ab = (const __bf16*)Araw + (size_t)(m0 + wave * 16 + sr) * K + sc;
  }
  f32x4 acc[4][4] = {};
  float4 pa[8];
  if constexpr (MODE == 0) {  // prologue prefetch: K-slab 0
#pragma unroll
    for (int s = 0; s < 2; s++) {
      pa[s * 4 + 0] = *(const float4*)(Af + s * 32);
      pa[s * 4 + 1] = *(const float4*)(Af + s * 32 + 4);
      pa[s * 4 + 2] = *(const float4*)(Af + (size_t)64 * K + s * 32);
      pa[s * 4 + 3] = *(const float4*)(Af + (size_t)64 * K + s * 32 + 4);
    }
  }
  for (int k0 = 0; k0 < K; k0 += 64) {
    // B staging first: flies while A converts/stages
#pragma unroll
    for (int s = 0; s < 2; s++) {
      glds16(Bb + k0 + s * 32, Bsl + s * 4096);
      glds16(Bb + 64 * K + k0 + s * 32, Bsl + s * 4096 + 2048);
    }
    if constexpr (MODE == 0) {
      // convert prefetched slab (loads issued last iteration -> latency hidden)
#pragma unroll
      for (int s = 0; s < 2; s++) {
        const float4 a0 = pa[s * 4 + 0], a1 = pa[s * 4 + 1];
        const float4 b0 = pa[s * 4 + 2], b1 = pa[s * 4 + 3];
        bf16x8 c0, c1;
        c0[0] = (__bf16)a0.x; c0[1] = (__bf16)a0.y; c0[2] = (__bf16)a0.z; c0[3] = (__bf16)a0.w;
        c0[4] = (__bf16)a1.x; c0[5] = (__bf16)a1.y; c0[6] = (__bf16)a1.z; c0[7] = (__bf16)a1.w;
        c1[0] = (__bf16)b0.x; c1[1] = (__bf16)b0.y; c1[2] = (__bf16)b0.z; c1[3] = (__bf16)b0.w;
        c1[4] = (__bf16)b1.x; c1[5] = (__bf16)b1.y; c1[6] = (__bf16)b1.z; c1[7] = (__bf16)b1.w;
        *(bf16x8*)(As + s * 4096 + (wave * 16 + sr) * 32 + sc) = c0;
        *(bf16x8*)(As + s * 4096 + (64 + wave * 16 + sr) * 32 + sc) = c1;
      }
    } else {
#pragma unroll
      for (int s = 0; s < 2; s++) {
        glds16(Ab + k0 + s * 32, Asl + s * 4096);
        glds16(Ab + 64 * K + k0 + s * 32, Asl + s * 4096 + 2048);
      }
    }
    __syncthreads();  // drains staging -> LDS visible
    if constexpr (MODE == 0) {  // issue next-slab loads; hidden under MFMA phase
      if (k0 + 64 < K) {
        const float* An = Af + k0 + 64;
#pragma unroll
        for (int s = 0; s < 2; s++) {
          pa[s * 4 + 0] = *(const float4*)(An + s * 32);
          pa[s * 4 + 1] = *(const float4*)(An + s * 32 + 4);
          pa[s * 4 + 2] = *(const float4*)(An + (size_t)64 * K + s * 32);
          pa[s * 4 + 3] = *(const float4*)(An + (size_t)64 * K + s * 32 + 4);
        }
      }
    }
#pragma unroll
    for (int s = 0; s < 2; s++) {
      bf16x8 af[4], bfr[4];
#pragma unroll
      for (int i = 0; i < 4; i++) {
        af[i] = *(const bf16x8*)(As + s * 4096 + (wm * 64 + i * 16 + l15) * 32 + quad * 8);
        bfr[i] = *(const bf16x8*)(Bs + s * 4096 + (wn * 64 + i * 16 + l15) * 32 + quad * 8);
      }
#pragma unroll
      for (int i = 0; i < 4; i++)
#pragma unroll
        for (int j = 0; j < 4; j++)
          acc[i][j] = MFMA16(af[i], bfr[j], acc[i][j]);
    }
    __syncthreads();  // protect LDS before next stage
  }
#pragma unroll
  for (int i = 0; i < 4; i++) {
    const int rowb = m0 + wm * 64 + i * 16 + quad * 4;
#pragma unroll
    for (int r = 0; r < 4; r++) {
      const int row = rowb + r;
      if constexpr (MODE == 0) {
        const int bb = row / 343, pos = row % 343;
#pragma unroll
        for (int j = 0; j < 4; j++) {
          const int col = n0 + wn * 64 + j * 16 + l15;
          const int two = col >> 9, hh = (col >> 5) & 15, d = col & 31;
          __bf16* dst = two ? (__bf16*)out1 : (__bf16*)out0;
          dst[((bb * 16 + hh) * 343 + pos) * 32 + d] = (__bf16)acc[i][j][r];
        }
      } else {
        float* o = (float*)out0;
#pragma unroll
        for (int j = 0; j < 4; j++) {
          const int col = n0 + wn * 64 + j * 16 + l15;
          o[row * 512 + col] = acc[i][j][r] + pbias[col];
        }
      }
    }
  }
}

// One workgroup per (b, h). Swapped QK^T (S^T = mfma(K, Q)) with PERMUTED key
// order so the S^T C-fragment IS the PV A-fragment after bf16 packing.
// Bias+mask are added via an extra MFMA per S-half: tables packed in A-operand
// layout (quads 0-1 = bias columns k=0..15, quads 2-3 = mask columns 16..31),
// multiplied by the constant selector B-frag B[k][j] = (k%16 == j), so
// (A.B)[key][q] = bias+mask lands in the C-preload on the matrix pipe.
// K bulk-staged in LDS; V transposed in LDS.
// launch_bounds (512,4): cap 128 regs -- (512,6)'s 85-reg cap caused massive
// scratch spilling (round-4: WRITE_SIZE 44->470 MB, dur 96->231 us).
__global__ void __launch_bounds__(512, 4)
attn_win(const __bf16* __restrict__ qs, const __bf16* __restrict__ kk,
         const __bf16* __restrict__ vv, const __bf16* __restrict__ bias_pk,
         const __bf16* __restrict__ mask_pk, __bf16* __restrict__ ao) {
  __shared__ __bf16 Ks[352 * 40];    // keys padded to 352 rows, stride 40
  __shared__ __bf16 Vt[32 * 360];    // V transposed [hd][key], stride 360
  const int bid = blockIdx.x;
  const int bh = (bid & 7) * 256 + (bid >> 3);  // XCD swizzle (2048 % 8 == 0)
  const int b = bh >> 4, h = bh & 15;
  const int tid = threadIdx.x;
  const int lane = tid & 63, wave = tid >> 6;
  const int quad = lane >> 4, l15 = lane & 15;
  const __bf16* ksrc = kk + (b * 16 + h) * 10976;
  const __bf16* vsrc = vv + (b * 16 + h) * 10976;
  for (int i = tid; i < 352 * 4; i += 512) {
    const int row = i >> 2, seg = (i & 3) * 8;
    bf16x8 val;
    if (row < 343) {
      val = *(const bf16x8*)(ksrc + row * 32 + seg);
    } else {
#pragma unroll
      for (int e = 0; e < 8; e++) val[e] = (__bf16)0.f;
    }
    *(bf16x8*)(Ks + row * 40 + seg) = val;
  }
  // zero-pad Vt cols 343..358 (reads reach col 351)
  Vt[(tid >> 4) * 360 + 343 + (tid & 15)] = (__bf16)0.f;
  for (int i = tid; i < 1372; i += 512) {  // 10976/8 vectorized transpose
    const int pos = i >> 2, seg = (i & 3) * 8;
    bf16x8 v = *(const bf16x8*)(vsrc + pos * 32 + seg);
#pragma unroll
    for (int e = 0; e < 8; e++) Vt[(seg + e) * 360 + pos] = v[e];
  }

  const int b2 = b >> 6, w = b & 63;
  const __bf16* qbase = qs + (b2 * 16 + h) * 10976;
  // per-lane table base: bias for quads 0-1, mask for quads 2-3
  const __bf16* tab = (quad < 2 ? bias_pk + h * 123904 : mask_pk + w * 123904)
                      + (quad & 1) * 128 + l15 * 8;
  const int nqt = (wave < 6) ? 3 : 2;  // 22 q-tiles over 8 waves

  bf16x8 aq[3];
#pragma unroll
  for (int t = 0; t < 3; t++) {
    int qt = wave + 8 * t; if (qt > 21) qt = 21;
    const int arow = qt * 16 + l15;
    const int arowc = arow < 343 ? arow : 342;  // clamp; padded rows discarded
    aq[t] = *(const bf16x8*)(qbase + arowc * 32 + quad * 8);
  }
  bf16x8 ones;  // B-frag of the "ones column": col 0 = 1, rest 0
  bf16x8 idf;   // selector B-frag: B[k][j] = (k%16 == j)
  {
    const __bf16 ov = (l15 == 0) ? (__bf16)1.f : (__bf16)0.f;
#pragma unroll
    for (int e = 0; e < 8; e++) {
      ones[e] = ov;
      idf[e] = ((quad & 1) * 8 + e == l15) ? (__bf16)1.f : (__bf16)0.f;
    }
  }
  const int krow = (l15 >> 2) * 8 + (l15 & 3);  // permuted key-row order
  __syncthreads();

  f32x4 o0[3], o1[3], o2[3];
#pragma unroll
  for (int t = 0; t < 3; t++)
#pragma unroll
    for (int r = 0; r < 4; r++) { o0[t][r] = 0.f; o1[t][r] = 0.f; o2[t][r] = 0.f; }

  for (int c = 0; c < 11; c++) {  // 11 chunks of 32 keys
    const bf16x8 bk0 = *(const bf16x8*)(Ks + (c * 32 + krow) * 40 + quad * 8);
    const bf16x8 bk1 = *(const bf16x8*)(Ks + (c * 32 + krow + 4) * 40 + quad * 8);
    const bf16x8 bv0 = *(const bf16x8*)(Vt + l15 * 360 + c * 32 + quad * 8);
    const bf16x8 bv1 = *(const bf16x8*)(Vt + (16 + l15) * 360 + c * 32 + quad * 8);
#pragma unroll
    for (int t = 0; t < 3; t++) {
      if (t >= nqt) break;
      const int qt = wave + 8 * t;
      const __bf16* tb = tab + (qt * 11 + c) * 512;
      const bf16x8 f0 = *(const bf16x8*)tb;          // A-frag, keys krow+0
      const bf16x8 f1 = *(const bf16x8*)(tb + 256);  // A-frag, keys krow+4
      const f32x4 z = {0.f, 0.f, 0.f, 0.f};
      __builtin_amdgcn_s_setprio(1);
      f32x4 s0 = MFMA16(f0, idf, z);   // C preload = bias+mask (log2 domain)
      f32x4 s1 = MFMA16(f1, idf, z);
      s0 = MFMA16(bk0, aq[t], s0);     // swapped: rows=keys (permuted), cols=q
      s1 = MFMA16(bk1, aq[t], s1);
#pragma unroll
      for (int r = 0; r < 4; r++) {
        s0[r] = __builtin_amdgcn_exp2f(s0[r]);
        s1[r] = __builtin_amdgcn_exp2f(s1[r]);
      }
      // S^T fragment (permuted key order) IS the PV A-fragment: just pack.
      u32x4v uv;
      uv[0] = pk2(s0[0], s0[1]); uv[1] = pk2(s0[2], s0[3]);
      uv[2] = pk2(s1[0], s1[1]); uv[3] = pk2(s1[2], s1[3]);
      const bf16x8 ap = __builtin_bit_cast(bf16x8, uv);
      o0[t] = MFMA16(ap, bv0, o0[t]);
      o1[t] = MFMA16(ap, bv1, o1[t]);
      o2[t] = MFMA16(ap, ones, o2[t]);  // row-sum of P via matrix pipe
      __builtin_amdgcn_s_setprio(0);
    }
  }

#pragma unroll
  for (int t = 0; t < 3; t++) {
    if (t >= nqt) break;
    const int qt = wave + 8 * t;
#pragma unroll
    for (int r = 0; r < 4; r++) {
      const float lsum = __shfl(o2[t][r], lane & 48);  // from l15==0 of my quad
      const float inv = __builtin_amdgcn_rcpf(lsum);
      const int row = qt * 16 + quad * 4 + r;
      if (row < 343) {
        __bf16* op = ao + (b * 343 + row) * 512 + h * 32;
        op[l15] = (__bf16)(o0[t][r] * inv);
        op[16 + l15] = (__bf16)(o1[t][r] * inv);
      }
    }
  }
}

extern "C" void kernel_launch(void* const* d_in, const int* in_sizes, int n_in,
                              void* d_out, int out_size, void* d_ws, size_t ws_size,
                              hipStream_t stream) {
  (void)in_sizes; (void)n_in; (void)out_size; (void)ws_size;
  const float* x      = (const float*)d_in[0];
  const float* mask   = (const float*)d_in[4];
  const float* qg     = (const float*)d_in[5];
  const float* kv_w   = (const float*)d_in[6];
  const float* proj_w = (const float*)d_in[7];
  const float* proj_b = (const float*)d_in[8];
  const float* rpb    = (const float*)d_in[9];

  // Workspace layout (16B aligned). x is consumed directly (f32) by gemm0's
  // fused convert staging; aob occupies the slot xb used to hold.
  char* ws = (char*)d_ws;
  __bf16* q_bf    = (__bf16*)(ws);               //    702,464  q*scale*log2e [2][16][343][32]
  __bf16* bias_pk = (__bf16*)(ws + 702464);      //  3,964,928  [16][22][11][2][2][16][8]
  __bf16* mask_pk = (__bf16*)(ws + 4667392);     // 15,859,712  [64][22][11][2][2][16][8]
  __bf16* kvw_b   = (__bf16*)(ws + 20527104);    //  1,048,576
  __bf16* projw_b = (__bf16*)(ws + 21575680);    //    524,288
  __bf16* kb      = (__bf16*)(ws + 22099968);    // 44,957,696  K bf16 [128][16][343][32]
  __bf16* vb      = (__bf16*)(ws + 67057664);    // 44,957,696  V bf16
  __bf16* aob     = (__bf16*)(ws + 112015360);   // 44,957,696  attn out bf16

  const float QSCALE = 0.17677669529663687f * LOG2E;  // hd^-0.5 * log2(e)

  cvt_scale<<<172, 256, 0, stream>>>(qg, q_bf, 43904, QSCALE);   // 351,232 elems = 43904*8
  cvt_scale<<<256, 256, 0, stream>>>(kv_w, kvw_b, 65536, 1.f);
  cvt_scale<<<128, 256, 0, stream>>>(proj_w, projw_b, 32768, 1.f);
  pack_bias<<<968, 256, 0, stream>>>(rpb, bias_pk);
  pack_mask<<<3872, 256, 0, stream>>>(mask, mask_pk);
  gemm_async<0><<<dim3(8, 343), 256, 0, stream>>>(x, kvw_b, 512, kb, vb, nullptr);
  attn_win<<<2048, 512, 0, stream>>>(q_bf, kb, vb, bias_pk, mask_pk, aob);
  gemm_async<1><<<dim3(4, 343), 256, 0, stream>>>(aob, projw_b, 512, d_out, nullptr, proj_b);
}